// Round 1
// baseline (364.638 us; speedup 1.0000x reference)
//
#include <hip/hip_runtime.h>
#include <cstdint>
#include <cstddef>

#define B_DIM 16
#define C_DIM 1024
#define N_DIM 2304   // 48*48

typedef _Float16 f16;
typedef _Float16 f16x8 __attribute__((ext_vector_type(8)));
typedef _Float16 f16x4 __attribute__((ext_vector_type(4)));
typedef float f32x4 __attribute__((ext_vector_type(4)));

__device__ __forceinline__ void gload_lds16(const void* g, void* l) {
  __builtin_amdgcn_global_load_lds(
      (const __attribute__((address_space(1))) unsigned int*)g,
      (__attribute__((address_space(3))) unsigned int*)l, 16, 0, 0);
}

// K1: x fp32 [C][N] -> qh f16 [C][N] (row-major) and qt f16 [N][C] (transposed)
__global__ __launch_bounds__(256)
void k_cast_transpose(const float* __restrict__ x, f16* __restrict__ qh,
                      f16* __restrict__ qt) {
  __shared__ f16 t[64][65];
  const int z = blockIdx.z;
  const int c0 = blockIdx.y * 64, n0 = blockIdx.x * 64;
  const int tid = threadIdx.x;
  const int r = tid >> 2;          // 0..63 (row within tile)
  const int cq = (tid & 3) << 4;   // 0,16,32,48 (col chunk)
  const float* xp = x + ((size_t)z * C_DIM + c0 + r) * N_DIM + n0 + cq;
  float4 v0 = ((const float4*)xp)[0];
  float4 v1 = ((const float4*)xp)[1];
  float4 v2 = ((const float4*)xp)[2];
  float4 v3 = ((const float4*)xp)[3];
  float vv[16] = {v0.x, v0.y, v0.z, v0.w, v1.x, v1.y, v1.z, v1.w,
                  v2.x, v2.y, v2.z, v2.w, v3.x, v3.y, v3.z, v3.w};
  f16 h[16];
#pragma unroll
  for (int j = 0; j < 16; ++j) h[j] = (f16)vv[j];
  f16* qp = qh + ((size_t)z * C_DIM + c0 + r) * N_DIM + n0 + cq;
  ((f16x8*)qp)[0] = *(const f16x8*)&h[0];
  ((f16x8*)qp)[1] = *(const f16x8*)&h[8];
#pragma unroll
  for (int j = 0; j < 16; ++j) t[r][cq + j] = h[j];
  __syncthreads();
  f16 o[16];
#pragma unroll
  for (int j = 0; j < 16; ++j) o[j] = t[cq + j][r];
  f16* tp = qt + ((size_t)z * N_DIM + n0 + r) * C_DIM + c0 + cq;
  ((f16x8*)tp)[0] = *(const f16x8*)&o[0];
  ((f16x8*)tp)[1] = *(const f16x8*)&o[8];
}

// K3: per row c of E (fp32, length C): attn = exp(min - e) / sum, written f16
// IN-PLACE over the row's own bytes (row stride stays C floats = 2C halves).
__global__ __launch_bounds__(256)
void k_softmax(float* __restrict__ eng) {
  const int c = blockIdx.x, z = blockIdx.y;
  float* erow = eng + ((size_t)z * C_DIM + c) * C_DIM;
  const int tid = threadIdx.x;
  float4 v = ((const float4*)erow)[tid];
  float lmin = fminf(fminf(v.x, v.y), fminf(v.z, v.w));
#pragma unroll
  for (int s = 32; s > 0; s >>= 1) lmin = fminf(lmin, __shfl_xor(lmin, s, 64));
  __shared__ float red[4];
  __shared__ float red2[4];
  const int lane = tid & 63, wid = tid >> 6;
  if (lane == 0) red[wid] = lmin;
  __syncthreads();
  const float m = fminf(fminf(red[0], red[1]), fminf(red[2], red[3]));
  float p0 = __expf(m - v.x), p1 = __expf(m - v.y);
  float p2 = __expf(m - v.z), p3 = __expf(m - v.w);
  float ls = p0 + p1 + p2 + p3;
#pragma unroll
  for (int s = 32; s > 0; s >>= 1) ls += __shfl_xor(ls, s, 64);
  if (lane == 0) red2[wid] = ls;
  __syncthreads();
  const float inv = 1.0f / (red2[0] + red2[1] + red2[2] + red2[3]);
  f16x4 o;
  o.x = (f16)(p0 * inv); o.y = (f16)(p1 * inv);
  o.z = (f16)(p2 * inv); o.w = (f16)(p3 * inv);
  *(f16x4*)((f16*)erow + tid * 4) = o;   // all reads done before first barrier
}

// NT GEMM: C[m][n] = sum_k A[m][k] * B[n][k]  (both row-major, K contiguous)
// 128x128 tile, BK=32, 4 waves (2x2), each wave 64x64 = 4x4 frags of 16x16x32.
// LDS XOR-swizzled (c16 ^= (row>>1)&3) so ds_read_b128 frag reads are 2-way max.
template <int KD, int LDA, int LDB, bool ADDX>
__global__ __launch_bounds__(256)
void k_gemm_nt(const f16* __restrict__ Ab, const f16* __restrict__ Bb,
               size_t astride, size_t bstride, float* __restrict__ Cb,
               size_t cstride, int ldc, const float* __restrict__ Xb) {
  __shared__ f16 As[128 * 32];
  __shared__ f16 Bs[128 * 32];
  const int tid = threadIdx.x, lane = tid & 63, wid = tid >> 6;
  const int wm = wid >> 1, wn = wid & 1;
  const int z = blockIdx.z;
  const int bm = blockIdx.y * 128, bn = blockIdx.x * 128;
  const f16* Ap = Ab + z * astride + (size_t)bm * LDA;
  const f16* Bp = Bb + z * bstride + (size_t)bn * LDB;

  int ldsoff[2];
  size_t goffA[2], goffB[2];
#pragma unroll
  for (int i = 0; i < 2; ++i) {
    const int o = (wid * 2 + i) * 1024 + lane * 16;  // byte off in 8KB tile
    const int rr = o >> 6;                            // tile row
    const int c16 = ((o >> 4) & 3) ^ ((rr >> 1) & 3); // inverse-swizzled src chunk
    ldsoff[i] = o;
    goffA[i] = (size_t)rr * LDA + c16 * 8;
    goffB[i] = (size_t)rr * LDB + c16 * 8;
  }

  f32x4 acc[4][4] = {};
  const int c16r = lane >> 4;
  int aro[4], bro[4];
#pragma unroll
  for (int i = 0; i < 4; ++i) {
    const int ra = wm * 64 + i * 16 + (lane & 15);
    aro[i] = ra * 64 + ((c16r ^ ((ra >> 1) & 3)) << 4);
    const int rb = wn * 64 + i * 16 + (lane & 15);
    bro[i] = rb * 64 + ((c16r ^ ((rb >> 1) & 3)) << 4);
  }

  for (int kk = 0; kk < KD; kk += 32) {
    gload_lds16(Ap + goffA[0] + kk, (char*)As + ldsoff[0]);
    gload_lds16(Ap + goffA[1] + kk, (char*)As + ldsoff[1]);
    gload_lds16(Bp + goffB[0] + kk, (char*)Bs + ldsoff[0]);
    gload_lds16(Bp + goffB[1] + kk, (char*)Bs + ldsoff[1]);
    __syncthreads();
    f16x8 af[4], bf[4];
#pragma unroll
    for (int i = 0; i < 4; ++i) af[i] = *(const f16x8*)((const char*)As + aro[i]);
#pragma unroll
    for (int i = 0; i < 4; ++i) bf[i] = *(const f16x8*)((const char*)Bs + bro[i]);
#pragma unroll
    for (int mi = 0; mi < 4; ++mi)
#pragma unroll
      for (int ni = 0; ni < 4; ++ni)
        acc[mi][ni] = __builtin_amdgcn_mfma_f32_16x16x32_f16(af[mi], bf[ni],
                                                             acc[mi][ni], 0, 0, 0);
    __syncthreads();
  }

  float* Cp = Cb + z * cstride;
#pragma unroll
  for (int mi = 0; mi < 4; ++mi)
#pragma unroll
    for (int ni = 0; ni < 4; ++ni)
#pragma unroll
      for (int j = 0; j < 4; ++j) {
        const int row = bm + wm * 64 + mi * 16 + c16r * 4 + j;
        const int col = bn + wn * 64 + ni * 16 + (lane & 15);
        const size_t idx = (size_t)row * ldc + col;
        float v = acc[mi][ni][j];
        if constexpr (ADDX) v += (Xb + z * cstride)[idx];
        Cp[idx] = v;
      }
}

extern "C" void kernel_launch(void* const* d_in, const int* in_sizes, int n_in,
                              void* d_out, int out_size, void* d_ws,
                              size_t ws_size, hipStream_t stream) {
  const float* x = (const float*)d_in[0];
  float* out = (float*)d_out;
  const size_t qbytes = (size_t)C_DIM * N_DIM * sizeof(f16);   // 4.72 MB
  const size_t ebytes = (size_t)C_DIM * C_DIM * sizeof(float); // 4.19 MB
  const size_t per_batch = 2 * qbytes + ebytes;                // 13.6 MB
  int G = (int)(ws_size / per_batch);
  if (G > B_DIM) G = B_DIM;
  if (G < 1) G = 1;

  f16* qh = (f16*)d_ws;
  f16* qt = qh + (size_t)G * C_DIM * N_DIM;
  float* eng = (float*)(qt + (size_t)G * C_DIM * N_DIM);

  for (int b0 = 0; b0 < B_DIM; b0 += G) {
    const int g = (B_DIM - b0 < G) ? (B_DIM - b0) : G;
    const float* xg = x + (size_t)b0 * C_DIM * N_DIM;
    float* og = out + (size_t)b0 * C_DIM * N_DIM;

    k_cast_transpose<<<dim3(N_DIM / 64, C_DIM / 64, g), 256, 0, stream>>>(
        xg, qh, qt);

    // E = qh . qh^T   (M=C, N=C, K=N_DIM)
    k_gemm_nt<N_DIM, N_DIM, N_DIM, false>
        <<<dim3(C_DIM / 128, C_DIM / 128, g), 256, 0, stream>>>(
            qh, qh, (size_t)C_DIM * N_DIM, (size_t)C_DIM * N_DIM, eng,
            (size_t)C_DIM * C_DIM, C_DIM, nullptr);

    // attn = softmax(min - E) written f16 in-place (row stride 2C halves)
    k_softmax<<<dim3(C_DIM, g, 1), 256, 0, stream>>>(eng);

    // out = attn . qt^T + x   (M=C, N=N_DIM, K=C; A stride 2C halves)
    k_gemm_nt<C_DIM, 2 * C_DIM, C_DIM, true>
        <<<dim3(N_DIM / 128, C_DIM / 128, g), 256, 0, stream>>>(
            (const f16*)eng, qt, (size_t)2 * C_DIM * C_DIM,
            (size_t)N_DIM * C_DIM, og, (size_t)C_DIM * N_DIM, N_DIM, xg);
  }
}

// Round 2
// 341.755 us; speedup vs baseline: 1.0670x; 1.0670x over previous
//
#include <hip/hip_runtime.h>
#include <cstdint>
#include <cstddef>

#define B_DIM 16
#define C_DIM 1024
#define N_DIM 2304   // 48*48

typedef _Float16 f16;
typedef _Float16 f16x8 __attribute__((ext_vector_type(8)));
typedef _Float16 f16x4 __attribute__((ext_vector_type(4)));
typedef float f32x4 __attribute__((ext_vector_type(4)));

__device__ __forceinline__ void gload_lds16(const void* g, void* l) {
  __builtin_amdgcn_global_load_lds(
      (const __attribute__((address_space(1))) unsigned int*)g,
      (__attribute__((address_space(3))) unsigned int*)l, 16, 0, 0);
}

// K1: x fp32 [C][N] -> qh f16 [C][N] (row-major) and qt f16 [N][C] (transposed)
__global__ __launch_bounds__(256)
void k_cast_transpose(const float* __restrict__ x, f16* __restrict__ qh,
                      f16* __restrict__ qt) {
  __shared__ f16 t[64][65];
  const int z = blockIdx.z;
  const int c0 = blockIdx.y * 64, n0 = blockIdx.x * 64;
  const int tid = threadIdx.x;
  const int r = tid >> 2;          // 0..63 (row within tile)
  const int cq = (tid & 3) << 4;   // 0,16,32,48 (col chunk)
  const float* xp = x + ((size_t)z * C_DIM + c0 + r) * N_DIM + n0 + cq;
  float4 v0 = ((const float4*)xp)[0];
  float4 v1 = ((const float4*)xp)[1];
  float4 v2 = ((const float4*)xp)[2];
  float4 v3 = ((const float4*)xp)[3];
  float vv[16] = {v0.x, v0.y, v0.z, v0.w, v1.x, v1.y, v1.z, v1.w,
                  v2.x, v2.y, v2.z, v2.w, v3.x, v3.y, v3.z, v3.w};
  f16 h[16];
#pragma unroll
  for (int j = 0; j < 16; ++j) h[j] = (f16)vv[j];
  f16* qp = qh + ((size_t)z * C_DIM + c0 + r) * N_DIM + n0 + cq;
  ((f16x8*)qp)[0] = *(const f16x8*)&h[0];
  ((f16x8*)qp)[1] = *(const f16x8*)&h[8];
#pragma unroll
  for (int j = 0; j < 16; ++j) t[r][cq + j] = h[j];
  __syncthreads();
  f16 o[16];
#pragma unroll
  for (int j = 0; j < 16; ++j) o[j] = t[cq + j][r];
  f16* tp = qt + ((size_t)z * N_DIM + n0 + r) * C_DIM + c0 + cq;
  ((f16x8*)tp)[0] = *(const f16x8*)&o[0];
  ((f16x8*)tp)[1] = *(const f16x8*)&o[8];
}

// K3: per row c of E (fp32, length C): attn = exp(min - e) / sum, written f16
// IN-PLACE over the row's own bytes (row stride stays C floats = 2C halves).
__global__ __launch_bounds__(256)
void k_softmax(float* __restrict__ eng) {
  const int c = blockIdx.x, z = blockIdx.y;
  float* erow = eng + ((size_t)z * C_DIM + c) * C_DIM;
  const int tid = threadIdx.x;
  float4 v = ((const float4*)erow)[tid];
  float lmin = fminf(fminf(v.x, v.y), fminf(v.z, v.w));
#pragma unroll
  for (int s = 32; s > 0; s >>= 1) lmin = fminf(lmin, __shfl_xor(lmin, s, 64));
  __shared__ float red[4];
  __shared__ float red2[4];
  const int lane = tid & 63, wid = tid >> 6;
  if (lane == 0) red[wid] = lmin;
  __syncthreads();
  const float m = fminf(fminf(red[0], red[1]), fminf(red[2], red[3]));
  float p0 = __expf(m - v.x), p1 = __expf(m - v.y);
  float p2 = __expf(m - v.z), p3 = __expf(m - v.w);
  float ls = p0 + p1 + p2 + p3;
#pragma unroll
  for (int s = 32; s > 0; s >>= 1) ls += __shfl_xor(ls, s, 64);
  if (lane == 0) red2[wid] = ls;
  __syncthreads();
  const float inv = 1.0f / (red2[0] + red2[1] + red2[2] + red2[3]);
  f16x4 o;
  o.x = (f16)(p0 * inv); o.y = (f16)(p1 * inv);
  o.z = (f16)(p2 * inv); o.w = (f16)(p3 * inv);
  *(f16x4*)((f16*)erow + tid * 4) = o;   // all reads done before first barrier
}

// NT GEMM, 128x128 tile, BK=32, 4 waves (2x2), wave = 64x64 = 4x4 x 16x16x32.
// 3-buffer LDS pipeline with counted vmcnt (T3/T4): stage tile t+2 while
// computing tile t; raw s_barrier (no implicit drain); vmcnt(8) steady state.
// XOR swizzle (c16 ^= (row>>1)&3) keeps ds_read_b128 conflict-free.
// SYM: A==B (E = q.q^T): grid.x enumerates upper-triangle blocks, epilogue
// mirror-writes the transposed tile.
template <int KD, int LDA, int LDB, bool ADDX, bool SYM>
__global__ __launch_bounds__(256)
void k_gemm_nt(const f16* __restrict__ Ab, const f16* __restrict__ Bb,
               size_t astride, size_t bstride, float* __restrict__ Cb,
               size_t cstride, int ldc, const float* __restrict__ Xb) {
  constexpr int NT = KD / 32;
  static_assert(NT >= 3, "pipeline needs >=3 K-tiles");
  __shared__ char lds[3 * 16384];   // per buf: A tile 8KB @0, B tile 8KB @8192
  const int tid = threadIdx.x, lane = tid & 63, wid = tid >> 6;
  const int wm = wid >> 1, wn = wid & 1;
  const int z = blockIdx.z;
  int bm, bn;
  if constexpr (SYM) {
    int l = blockIdx.x, bi = 0;
    while (l >= 8 - bi) { l -= 8 - bi; ++bi; }   // C/128 = 8 row-blocks
    bm = bi * 128; bn = (bi + l) * 128;
  } else {
    bm = blockIdx.y * 128; bn = blockIdx.x * 128;
  }
  const f16* Ap = Ab + z * astride + (size_t)bm * LDA;
  const f16* Bp = Bb + z * bstride + (size_t)bn * LDB;

  int ldsoff[2];
  size_t goffA[2], goffB[2];
#pragma unroll
  for (int i = 0; i < 2; ++i) {
    const int o = (wid * 2 + i) * 1024 + lane * 16;  // byte off in 8KB tile
    const int rr = o >> 6;                            // tile row
    const int c16 = ((o >> 4) & 3) ^ ((rr >> 1) & 3); // inverse-swizzled src chunk
    ldsoff[i] = o;
    goffA[i] = (size_t)rr * LDA + c16 * 8;
    goffB[i] = (size_t)rr * LDB + c16 * 8;
  }

  f32x4 acc[4][4] = {};
  const int c16r = lane >> 4;
  int aro[4], bro[4];
#pragma unroll
  for (int i = 0; i < 4; ++i) {
    const int ra = wm * 64 + i * 16 + (lane & 15);
    aro[i] = ra * 64 + ((c16r ^ ((ra >> 1) & 3)) << 4);
    const int rb = wn * 64 + i * 16 + (lane & 15);
    bro[i] = rb * 64 + ((c16r ^ ((rb >> 1) & 3)) << 4);
  }

  auto STAGE = [&](int buf, int t) {
    char* base = lds + buf * 16384;
    const int kk = t * 32;
    gload_lds16(Ap + goffA[0] + kk, base + ldsoff[0]);
    gload_lds16(Ap + goffA[1] + kk, base + ldsoff[1]);
    gload_lds16(Bp + goffB[0] + kk, base + 8192 + ldsoff[0]);
    gload_lds16(Bp + goffB[1] + kk, base + 8192 + ldsoff[1]);
  };
  auto COMPUTE = [&](int buf) {
    const char* base = lds + buf * 16384;
    f16x8 af[4], bf[4];
#pragma unroll
    for (int i = 0; i < 4; ++i) af[i] = *(const f16x8*)(base + aro[i]);
#pragma unroll
    for (int i = 0; i < 4; ++i) bf[i] = *(const f16x8*)(base + 8192 + bro[i]);
    __builtin_amdgcn_s_setprio(1);
#pragma unroll
    for (int mi = 0; mi < 4; ++mi)
#pragma unroll
      for (int ni = 0; ni < 4; ++ni)
        acc[mi][ni] = __builtin_amdgcn_mfma_f32_16x16x32_f16(af[mi], bf[ni],
                                                             acc[mi][ni], 0, 0, 0);
    __builtin_amdgcn_s_setprio(0);
  };

  STAGE(0, 0);
  STAGE(1, 1);
  int cb = 0, stb = 2;
  for (int t = 0; t + 2 < NT; ++t) {
    STAGE(stb, t + 2);
    asm volatile("s_waitcnt vmcnt(8)" ::: "memory");  // tile t landed (t+1,t+2 in flight)
    __builtin_amdgcn_s_barrier();
    __builtin_amdgcn_sched_barrier(0);
    COMPUTE(cb);
    __builtin_amdgcn_sched_barrier(0);
    __builtin_amdgcn_s_barrier();                      // reads done before next STAGE overwrites
    cb = (cb == 2) ? 0 : cb + 1;
    stb = (stb == 2) ? 0 : stb + 1;
  }
  asm volatile("s_waitcnt vmcnt(4)" ::: "memory");     // tile NT-2 landed
  __builtin_amdgcn_s_barrier();
  __builtin_amdgcn_sched_barrier(0);
  COMPUTE(cb);
  cb = (cb == 2) ? 0 : cb + 1;
  asm volatile("s_waitcnt vmcnt(0)" ::: "memory");     // tile NT-1 landed
  __builtin_amdgcn_s_barrier();
  __builtin_amdgcn_sched_barrier(0);
  COMPUTE(cb);

  float* Cp = Cb + z * cstride;
#pragma unroll
  for (int mi = 0; mi < 4; ++mi)
#pragma unroll
    for (int ni = 0; ni < 4; ++ni) {
      const int row0 = bm + wm * 64 + mi * 16 + c16r * 4;
      const int col = bn + wn * 64 + ni * 16 + (lane & 15);
      if constexpr (SYM) {
#pragma unroll
        for (int j = 0; j < 4; ++j)
          Cp[(size_t)(row0 + j) * ldc + col] = acc[mi][ni][j];
        if (bm != bn) {  // mirror tile: E[col][row], 4 consecutive floats/lane
          float4 mv;
          mv.x = acc[mi][ni][0]; mv.y = acc[mi][ni][1];
          mv.z = acc[mi][ni][2]; mv.w = acc[mi][ni][3];
          *(float4*)&Cp[(size_t)col * ldc + row0] = mv;
        }
      } else {
#pragma unroll
        for (int j = 0; j < 4; ++j) {
          const size_t idx = (size_t)(row0 + j) * ldc + col;
          float v = acc[mi][ni][j];
          if constexpr (ADDX) v += (Xb + z * cstride)[idx];
          Cp[idx] = v;
        }
      }
    }
}

extern "C" void kernel_launch(void* const* d_in, const int* in_sizes, int n_in,
                              void* d_out, int out_size, void* d_ws,
                              size_t ws_size, hipStream_t stream) {
  const float* x = (const float*)d_in[0];
  float* out = (float*)d_out;
  const size_t qbytes = (size_t)C_DIM * N_DIM * sizeof(f16);   // 4.72 MB
  const size_t ebytes = (size_t)C_DIM * C_DIM * sizeof(float); // 4.19 MB
  const size_t per_batch = 2 * qbytes + ebytes;                // 13.6 MB
  int G = (int)(ws_size / per_batch);
  if (G > B_DIM) G = B_DIM;
  if (G < 1) G = 1;

  f16* qh = (f16*)d_ws;
  f16* qt = qh + (size_t)G * C_DIM * N_DIM;
  float* eng = (float*)(qt + (size_t)G * C_DIM * N_DIM);

  for (int b0 = 0; b0 < B_DIM; b0 += G) {
    const int g = (B_DIM - b0 < G) ? (B_DIM - b0) : G;
    const float* xg = x + (size_t)b0 * C_DIM * N_DIM;
    float* og = out + (size_t)b0 * C_DIM * N_DIM;

    k_cast_transpose<<<dim3(N_DIM / 64, C_DIM / 64, g), 256, 0, stream>>>(
        xg, qh, qt);

    // E = qh . qh^T  (symmetric: 36 upper-triangle blocks, mirrored writes)
    k_gemm_nt<N_DIM, N_DIM, N_DIM, false, true>
        <<<dim3(36, 1, g), 256, 0, stream>>>(
            qh, qh, (size_t)C_DIM * N_DIM, (size_t)C_DIM * N_DIM, eng,
            (size_t)C_DIM * C_DIM, C_DIM, nullptr);

    // attn = softmax(min - E) written f16 in-place (row stride 2C halves)
    k_softmax<<<dim3(C_DIM, g, 1), 256, 0, stream>>>(eng);

    // out = attn . qt^T + x   (M=C, N=N_DIM, K=C; A stride 2C halves)
    k_gemm_nt<C_DIM, 2 * C_DIM, C_DIM, true, false>
        <<<dim3(N_DIM / 128, C_DIM / 128, g), 256, 0, stream>>>(
            (const f16*)eng, qt, (size_t)2 * C_DIM * C_DIM,
            (size_t)N_DIM * C_DIM, og, (size_t)C_DIM * N_DIM, N_DIM, xg);
  }
}

// Round 3
// 306.846 us; speedup vs baseline: 1.1883x; 1.1138x over previous
//
#include <hip/hip_runtime.h>
#include <cstdint>
#include <cstddef>

#define B_DIM 16
#define C_DIM 1024
#define N_DIM 2304   // 48*48

typedef _Float16 f16;
typedef _Float16 f16x8 __attribute__((ext_vector_type(8)));
typedef _Float16 f16x4 __attribute__((ext_vector_type(4)));
typedef float f32x4 __attribute__((ext_vector_type(4)));

__device__ __forceinline__ void gload_lds16(const void* g, void* l) {
  __builtin_amdgcn_global_load_lds(
      (const __attribute__((address_space(1))) unsigned int*)g,
      (__attribute__((address_space(3))) unsigned int*)l, 16, 0, 0);
}

// K1: x fp32 [C][N] -> qh f16 [C][N] (row-major) and qt f16 [N][C] (transposed)
__global__ __launch_bounds__(256)
void k_cast_transpose(const float* __restrict__ x, f16* __restrict__ qh,
                      f16* __restrict__ qt) {
  __shared__ f16 t[64][65];
  const int z = blockIdx.z;
  const int c0 = blockIdx.y * 64, n0 = blockIdx.x * 64;
  const int tid = threadIdx.x;
  const int r = tid >> 2;          // 0..63 (row within tile)
  const int cq = (tid & 3) << 4;   // 0,16,32,48 (col chunk)
  const float* xp = x + ((size_t)z * C_DIM + c0 + r) * N_DIM + n0 + cq;
  float4 v0 = ((const float4*)xp)[0];
  float4 v1 = ((const float4*)xp)[1];
  float4 v2 = ((const float4*)xp)[2];
  float4 v3 = ((const float4*)xp)[3];
  float vv[16] = {v0.x, v0.y, v0.z, v0.w, v1.x, v1.y, v1.z, v1.w,
                  v2.x, v2.y, v2.z, v2.w, v3.x, v3.y, v3.z, v3.w};
  f16 h[16];
#pragma unroll
  for (int j = 0; j < 16; ++j) h[j] = (f16)vv[j];
  f16* qp = qh + ((size_t)z * C_DIM + c0 + r) * N_DIM + n0 + cq;
  ((f16x8*)qp)[0] = *(const f16x8*)&h[0];
  ((f16x8*)qp)[1] = *(const f16x8*)&h[8];
#pragma unroll
  for (int j = 0; j < 16; ++j) t[r][cq + j] = h[j];
  __syncthreads();
  f16 o[16];
#pragma unroll
  for (int j = 0; j < 16; ++j) o[j] = t[cq + j][r];
  f16* tp = qt + ((size_t)z * N_DIM + n0 + r) * C_DIM + c0 + cq;
  ((f16x8*)tp)[0] = *(const f16x8*)&o[0];
  ((f16x8*)tp)[1] = *(const f16x8*)&o[8];
}

// K3: per row c of E (fp32, length C): attn = exp(min - e) / sum, written f16
// IN-PLACE over the row's own bytes (row stride stays C floats = 2C halves).
__global__ __launch_bounds__(256)
void k_softmax(float* __restrict__ eng) {
  const int c = blockIdx.x, z = blockIdx.y;
  float* erow = eng + ((size_t)z * C_DIM + c) * C_DIM;
  const int tid = threadIdx.x;
  float4 v = ((const float4*)erow)[tid];
  float lmin = fminf(fminf(v.x, v.y), fminf(v.z, v.w));
#pragma unroll
  for (int s = 32; s > 0; s >>= 1) lmin = fminf(lmin, __shfl_xor(lmin, s, 64));
  __shared__ float red[4];
  __shared__ float red2[4];
  const int lane = tid & 63, wid = tid >> 6;
  if (lane == 0) red[wid] = lmin;
  __syncthreads();
  const float m = fminf(fminf(red[0], red[1]), fminf(red[2], red[3]));
  float p0 = __expf(m - v.x), p1 = __expf(m - v.y);
  float p2 = __expf(m - v.z), p3 = __expf(m - v.w);
  float ls = p0 + p1 + p2 + p3;
#pragma unroll
  for (int s = 32; s > 0; s >>= 1) ls += __shfl_xor(ls, s, 64);
  if (lane == 0) red2[wid] = ls;
  __syncthreads();
  const float inv = 1.0f / (red2[0] + red2[1] + red2[2] + red2[3]);
  f16x4 o;
  o.x = (f16)(p0 * inv); o.y = (f16)(p1 * inv);
  o.z = (f16)(p2 * inv); o.w = (f16)(p3 * inv);
  *(f16x4*)((f16*)erow + tid * 4) = o;   // all reads done before first barrier
}

// ---------------- 256x256 8-phase NT GEMM (T2+T3+T4+T5) ------------------
// 512 thr = 8 waves (2M x 4N); wave tile 128x64; BK=64 (2 K-planes of 32).
// LDS 128KB: A[2 dbuf][2 plane][256][32] f16 @0, B same @65536.
// Per-plane rows are 64B with chunk^=(row>>1)&3 swizzle (0-conflict, R1-proven).
// 8 phases per iteration (2 K-tiles): quadrant order (A0B0)(A0B1)(A1B1)(A1B0).
// Stage stream: p0:Tb.A1 p1:Tb.B0 p2:T+2.A0 p3:T+2.B1 p4:T+2.A1 p5:T+2.B0
//               p6:T+3.A0 p7:T+3.B1.  Waits: vmcnt(4) end-p3 / end-p7.

#define BARR __builtin_amdgcn_s_barrier()
#define SBR __builtin_amdgcn_sched_barrier(0)
#define LGKM0 asm volatile("s_waitcnt lgkmcnt(0)" ::: "memory")
#define VM4 asm volatile("s_waitcnt vmcnt(4)" ::: "memory")
#define VM0 asm volatile("s_waitcnt vmcnt(0)" ::: "memory")
#define PRIO1 __builtin_amdgcn_s_setprio(1)
#define PRIO0 __builtin_amdgcn_s_setprio(0)

#define STA(KT, H) { const int d_ = (KT) & 1;                                  \
    const f16* g_ = Ap + ((H) ? gA1 : gA0) + (size_t)(KT) * 64;                \
    char* l_ = sh + d_ * 32768 + (H) * 8192 + tid * 16;                        \
    gload_lds16(g_, l_); gload_lds16(g_ + 32, l_ + 16384); }

#define STB(KT, H) { const int d_ = (KT) & 1;                                  \
    const f16* g_ = Bp + ((H) ? gB1 : gB0) + (size_t)(KT) * 64;                \
    char* l_ = sh + 65536 + d_ * 32768 + (H) * 8192 + tid * 16;                \
    gload_lds16(g_, l_); gload_lds16(g_ + 32, l_ + 16384); }

#define RDA(D, MH) _Pragma("unroll") for (int j_ = 0; j_ < 4; ++j_)            \
    _Pragma("unroll") for (int p_ = 0; p_ < 2; ++p_)                           \
      a[j_ * 2 + p_] = *(const f16x8*)(sh + (D) * 32768 + p_ * 16384 +         \
                                       aoff[(MH) * 4 + j_]);

#define RDB(D, NH, BB) _Pragma("unroll") for (int i_ = 0; i_ < 2; ++i_)        \
    _Pragma("unroll") for (int p_ = 0; p_ < 2; ++p_)                           \
      BB[i_ * 2 + p_] = *(const f16x8*)(sh + 65536 + (D) * 32768 +             \
                                        p_ * 16384 + boff[(NH) * 2 + i_]);

#define MMQ(MH, NH, BB) _Pragma("unroll") for (int j_ = 0; j_ < 4; ++j_)       \
    _Pragma("unroll") for (int i_ = 0; i_ < 2; ++i_)                           \
    _Pragma("unroll") for (int k_ = 0; k_ < 2; ++k_)                           \
      acc[(MH) * 4 + j_][(NH) * 2 + i_] =                                      \
          __builtin_amdgcn_mfma_f32_16x16x32_f16(                              \
              a[j_ * 2 + k_], BB[i_ * 2 + k_],                                 \
              acc[(MH) * 4 + j_][(NH) * 2 + i_], 0, 0, 0);

#define ITER(TA, LAST) {                                                       \
    const int tb_ = (TA) + 1;                                                  \
    /* P0 (A0,B0) on buf0 */                                                   \
    RDA(0, 0); RDB(0, 0, b0); STA(tb_, 1);                                     \
    BARR; LGKM0; SBR; PRIO1; MMQ(0, 0, b0); PRIO0; BARR; SBR;                  \
    /* P1 (A0,B1) */                                                           \
    RDB(0, 1, b1); STB(tb_, 0);                                                \
    BARR; LGKM0; SBR; PRIO1; MMQ(0, 1, b1); PRIO0; BARR; SBR;                  \
    /* P2 (A1,B1) */                                                           \
    RDA(0, 1); if (!(LAST)) STA((TA) + 2, 0);                                  \
    BARR; LGKM0; SBR; PRIO1; MMQ(1, 1, b1); PRIO0; BARR; SBR;                  \
    /* P3 (A1,B0) */                                                           \
    if (!(LAST)) STB((TA) + 2, 1);                                             \
    BARR; LGKM0; SBR; PRIO1; MMQ(1, 0, b0); PRIO0;                             \
    if (LAST) { VM0; } else { VM4; } BARR; SBR;                                \
    /* P4 (A0,B0) on buf1 */                                                   \
    RDA(1, 0); RDB(1, 0, b0); if (!(LAST)) STA((TA) + 2, 1);                   \
    BARR; LGKM0; SBR; PRIO1; MMQ(0, 0, b0); PRIO0; BARR; SBR;                  \
    /* P5 (A0,B1) */                                                           \
    RDB(1, 1, b1); if (!(LAST)) STB((TA) + 2, 0);                              \
    BARR; LGKM0; SBR; PRIO1; MMQ(0, 1, b1); PRIO0; BARR; SBR;                  \
    /* P6 (A1,B1) */                                                           \
    RDA(1, 1); if (!(LAST)) STA((TA) + 3, 0);                                  \
    BARR; LGKM0; SBR; PRIO1; MMQ(1, 1, b1); PRIO0; BARR; SBR;                  \
    /* P7 (A1,B0) */                                                           \
    if (!(LAST)) STB((TA) + 3, 1);                                             \
    BARR; LGKM0; SBR; PRIO1; MMQ(1, 0, b0); PRIO0;                             \
    if (!(LAST)) { VM4; } BARR; SBR; }

template <int KD, int LDA, int LDB, bool ADDX>
__global__ __launch_bounds__(512, 2)
void k_gemm256(const f16* __restrict__ Ab, const f16* __restrict__ Bb,
               size_t astride, size_t bstride, float* __restrict__ Cb,
               size_t cstride, int ldc, const float* __restrict__ Xb) {
  constexpr int NT = KD / 64, NI = NT / 2;
  static_assert(KD % 128 == 0 && NT >= 4, "need even #tiles >= 4");
  __shared__ char sh[131072];
  const int tid = threadIdx.x, lane = tid & 63, wid = tid >> 6;
  const int wm = wid >> 2, wn = wid & 3;   // 2 x 4 waves
  const int z = blockIdx.z;
  const int bm = blockIdx.y * 256, bn = blockIdx.x * 256;
  const f16* Ap = Ab + z * astride + (size_t)bm * LDA;
  const f16* Bp = Bb + z * bstride + (size_t)bn * LDB;

  // staging offsets: thread t covers row rq=t>>2 (of a 128-row half), src
  // chunk cpr = (t&3) ^ ((t>>3)&3)  (inverse swizzle); LDS dest is linear.
  const int rq = tid >> 2;
  const int cpr = (tid & 3) ^ ((tid >> 3) & 3);
  const size_t gA0 = (size_t)rq * LDA + cpr * 8;
  const size_t gA1 = gA0 + (size_t)128 * LDA;
  const size_t gB0 = (size_t)rq * LDB + cpr * 8;
  const size_t gB1 = gB0 + (size_t)128 * LDB;

  // prologue: T0.{A0,B0,B1,A1}, T1.{A0,B1}; keep last 2 halves in flight
  STA(0, 0); STB(0, 0); STB(0, 1); STA(0, 1);
  STA(1, 0); STB(1, 1);

  // fragment read offsets (swizzled)
  int aoff[8], boff[4];
#pragma unroll
  for (int mi = 0; mi < 8; ++mi) {
    const int rt = ((mi < 4) ? wm * 64 + mi * 16
                             : 128 + wm * 64 + (mi - 4) * 16) + (lane & 15);
    aoff[mi] = rt * 64 + ((((lane >> 4) ^ (rt >> 1)) & 3) << 4);
  }
#pragma unroll
  for (int ni = 0; ni < 4; ++ni) {
    const int rb = ((ni < 2) ? wn * 32 + ni * 16
                             : 128 + wn * 32 + (ni - 2) * 16) + (lane & 15);
    boff[ni] = rb * 64 + ((((lane >> 4) ^ (rb >> 1)) & 3) << 4);
  }

  f32x4 acc[8][4] = {};
  f16x8 a[8], b0[4], b1[4];

  VM4; BARR; SBR;

  for (int it = 0; it < NI - 1; ++it) { ITER(2 * it, false); }
  ITER(2 * (NI - 1), true);

  // epilogue
  float* Cp = Cb + z * cstride;
  const float* Xp = Xb + z * cstride;
#pragma unroll
  for (int mi = 0; mi < 8; ++mi) {
    const int row0 = bm + ((mi < 4) ? wm * 64 + mi * 16
                                    : 128 + wm * 64 + (mi - 4) * 16) +
                     (lane >> 4) * 4;
#pragma unroll
    for (int ni = 0; ni < 4; ++ni) {
      const int col = bn + ((ni < 2) ? wn * 32 + ni * 16
                                     : 128 + wn * 32 + (ni - 2) * 16) +
                      (lane & 15);
#pragma unroll
      for (int j = 0; j < 4; ++j) {
        const size_t idx = (size_t)(row0 + j) * ldc + col;
        float v = acc[mi][ni][j];
        if constexpr (ADDX) v += Xp[idx];
        Cp[idx] = v;
      }
    }
  }
}

extern "C" void kernel_launch(void* const* d_in, const int* in_sizes, int n_in,
                              void* d_out, int out_size, void* d_ws,
                              size_t ws_size, hipStream_t stream) {
  const float* x = (const float*)d_in[0];
  float* out = (float*)d_out;
  const size_t qbytes = (size_t)C_DIM * N_DIM * sizeof(f16);   // 4.72 MB
  const size_t ebytes = (size_t)C_DIM * C_DIM * sizeof(float); // 4.19 MB
  const size_t per_batch = 2 * qbytes + ebytes;                // 13.6 MB
  int G = (int)(ws_size / per_batch);
  if (G > B_DIM) G = B_DIM;
  if (G < 1) G = 1;

  f16* qh = (f16*)d_ws;
  f16* qt = qh + (size_t)G * C_DIM * N_DIM;
  float* eng = (float*)(qt + (size_t)G * C_DIM * N_DIM);

  for (int b0 = 0; b0 < B_DIM; b0 += G) {
    const int g = (B_DIM - b0 < G) ? (B_DIM - b0) : G;
    const float* xg = x + (size_t)b0 * C_DIM * N_DIM;
    float* og = out + (size_t)b0 * C_DIM * N_DIM;

    k_cast_transpose<<<dim3(N_DIM / 64, C_DIM / 64, g), 256, 0, stream>>>(
        xg, qh, qt);

    // E = qh . qh^T  (M=N=C, K=N_DIM); full grid = 256 blocks = 1/CU
    k_gemm256<N_DIM, N_DIM, N_DIM, false>
        <<<dim3(C_DIM / 256, C_DIM / 256, g), 512, 0, stream>>>(
            qh, qh, (size_t)C_DIM * N_DIM, (size_t)C_DIM * N_DIM, eng,
            (size_t)C_DIM * C_DIM, C_DIM, nullptr);

    // attn = softmax(min - E) written f16 in-place (row stride 2C halves)
    k_softmax<<<dim3(C_DIM, g, 1), 256, 0, stream>>>(eng);

    // out = attn . qt^T + x   (M=C, N=N_DIM, K=C; A stride 2C halves)
    k_gemm256<C_DIM, 2 * C_DIM, C_DIM, true>
        <<<dim3(N_DIM / 256, C_DIM / 256, g), 512, 0, stream>>>(
            (const f16*)eng, qt, (size_t)2 * C_DIM * C_DIM,
            (size_t)N_DIM * C_DIM, og, (size_t)C_DIM * N_DIM, N_DIM, xg);
  }
}

// Round 4
// 278.319 us; speedup vs baseline: 1.3101x; 1.1025x over previous
//
#include <hip/hip_runtime.h>
#include <cstdint>
#include <cstddef>

#define B_DIM 16
#define C_DIM 1024
#define N_DIM 2304   // 48*48

typedef _Float16 f16;
typedef _Float16 f16x8 __attribute__((ext_vector_type(8)));
typedef _Float16 f16x4 __attribute__((ext_vector_type(4)));
typedef float f32x4 __attribute__((ext_vector_type(4)));

__device__ __forceinline__ void gload_lds16(const void* g, void* l) {
  __builtin_amdgcn_global_load_lds(
      (const __attribute__((address_space(1))) unsigned int*)g,
      (__attribute__((address_space(3))) unsigned int*)l, 16, 0, 0);
}

// K1: x fp32 [C][N] -> qh f16 [C][N] (row-major) and qt f16 [N][C] (transposed)
__global__ __launch_bounds__(256)
void k_cast_transpose(const float* __restrict__ x, f16* __restrict__ qh,
                      f16* __restrict__ qt) {
  __shared__ f16 t[64][65];
  const int z = blockIdx.z;
  const int c0 = blockIdx.y * 64, n0 = blockIdx.x * 64;
  const int tid = threadIdx.x;
  const int r = tid >> 2;          // 0..63 (row within tile)
  const int cq = (tid & 3) << 4;   // 0,16,32,48 (col chunk)
  const float* xp = x + ((size_t)z * C_DIM + c0 + r) * N_DIM + n0 + cq;
  float4 v0 = ((const float4*)xp)[0];
  float4 v1 = ((const float4*)xp)[1];
  float4 v2 = ((const float4*)xp)[2];
  float4 v3 = ((const float4*)xp)[3];
  float vv[16] = {v0.x, v0.y, v0.z, v0.w, v1.x, v1.y, v1.z, v1.w,
                  v2.x, v2.y, v2.z, v2.w, v3.x, v3.y, v3.z, v3.w};
  f16 h[16];
#pragma unroll
  for (int j = 0; j < 16; ++j) h[j] = (f16)vv[j];
  f16* qp = qh + ((size_t)z * C_DIM + c0 + r) * N_DIM + n0 + cq;
  ((f16x8*)qp)[0] = *(const f16x8*)&h[0];
  ((f16x8*)qp)[1] = *(const f16x8*)&h[8];
#pragma unroll
  for (int j = 0; j < 16; ++j) t[r][cq + j] = h[j];
  __syncthreads();
  f16 o[16];
#pragma unroll
  for (int j = 0; j < 16; ++j) o[j] = t[cq + j][r];
  f16* tp = qt + ((size_t)z * N_DIM + n0 + r) * C_DIM + c0 + cq;
  ((f16x8*)tp)[0] = *(const f16x8*)&o[0];
  ((f16x8*)tp)[1] = *(const f16x8*)&o[8];
}

// K3: one WAVE per row of E: attn = exp(min - e)/sum, f16 in-place.
// 4 waves (4 rows) per block, no barriers, no LDS.
__global__ __launch_bounds__(256)
void k_softmax(float* __restrict__ eng) {
  const int w = threadIdx.x >> 6, lane = threadIdx.x & 63;
  const int c = blockIdx.x * 4 + w, z = blockIdx.y;
  float* erow = eng + ((size_t)z * C_DIM + c) * C_DIM;
  float4 v[4];
#pragma unroll
  for (int i = 0; i < 4; ++i) v[i] = ((const float4*)erow)[lane + i * 64];
  float lmin = v[0].x;
#pragma unroll
  for (int i = 0; i < 4; ++i)
    lmin = fminf(lmin, fminf(fminf(v[i].x, v[i].y), fminf(v[i].z, v[i].w)));
#pragma unroll
  for (int s = 32; s > 0; s >>= 1) lmin = fminf(lmin, __shfl_xor(lmin, s, 64));
  float p[16];
  float ls = 0.f;
#pragma unroll
  for (int i = 0; i < 4; ++i) {
    p[i * 4 + 0] = __expf(lmin - v[i].x);
    p[i * 4 + 1] = __expf(lmin - v[i].y);
    p[i * 4 + 2] = __expf(lmin - v[i].z);
    p[i * 4 + 3] = __expf(lmin - v[i].w);
    ls += p[i * 4] + p[i * 4 + 1] + p[i * 4 + 2] + p[i * 4 + 3];
  }
#pragma unroll
  for (int s = 32; s > 0; s >>= 1) ls += __shfl_xor(ls, s, 64);
  const float inv = 1.0f / ls;
#pragma unroll
  for (int i = 0; i < 4; ++i) {
    f16x4 o;
    o.x = (f16)(p[i * 4 + 0] * inv); o.y = (f16)(p[i * 4 + 1] * inv);
    o.z = (f16)(p[i * 4 + 2] * inv); o.w = (f16)(p[i * 4 + 3] * inv);
    *(f16x4*)((f16*)erow + (lane + i * 64) * 4) = o;
  }
}

// ---------------- 256x256 8-phase NT GEMM (T1+T2+T3+T4+T5) ------------------
// 512 thr = 8 waves (2M x 4N); wave tile 128x64; BK=64 (2 K-planes of 32).
// LDS 128KB: A[2 dbuf][2 plane][256][32] f16 @0, B same @65536.
// Swizzle chunk^=(row>>1)&3 (0-conflict, proven R1/R2).
// DEEP stage schedule: iter I computes tiles 2I,2I+1 and stages tiles
// 2I+2 (P1,P2,P3) and 2I+3 (P5,P6,P7). Each LDS slot is staged only after
// the phase-barrier following its last ds_read. vmcnt(8) at end-P3/end-P7:
// at each wait exactly 16 loads outstanding, waited-on 8 issued >=5 phases
// earlier (~>=1000cy > HBM latency).

#define BARR __builtin_amdgcn_s_barrier()
#define SBR __builtin_amdgcn_sched_barrier(0)
#define LGKM0 asm volatile("s_waitcnt lgkmcnt(0)" ::: "memory")
#define VM8 asm volatile("s_waitcnt vmcnt(8)" ::: "memory")
#define VM0 asm volatile("s_waitcnt vmcnt(0)" ::: "memory")
#define PRIO1 __builtin_amdgcn_s_setprio(1)
#define PRIO0 __builtin_amdgcn_s_setprio(0)

#define STA(KT, H) { const int d_ = (KT) & 1;                                  \
    const f16* g_ = Ap + ((H) ? gA1 : gA0) + (size_t)(KT) * 64;                \
    char* l_ = sh + d_ * 32768 + (H) * 8192 + tid * 16;                        \
    gload_lds16(g_, l_); gload_lds16(g_ + 32, l_ + 16384); }

#define STB(KT, H) { const int d_ = (KT) & 1;                                  \
    const f16* g_ = Bp + ((H) ? gB1 : gB0) + (size_t)(KT) * 64;                \
    char* l_ = sh + 65536 + d_ * 32768 + (H) * 8192 + tid * 16;                \
    gload_lds16(g_, l_); gload_lds16(g_ + 32, l_ + 16384); }

#define RDA(D, MH) _Pragma("unroll") for (int j_ = 0; j_ < 4; ++j_)            \
    _Pragma("unroll") for (int p_ = 0; p_ < 2; ++p_)                           \
      a[j_ * 2 + p_] = *(const f16x8*)(sh + (D) * 32768 + p_ * 16384 +         \
                                       aoff[(MH) * 4 + j_]);

#define RDB(D, NH, BB) _Pragma("unroll") for (int i_ = 0; i_ < 2; ++i_)        \
    _Pragma("unroll") for (int p_ = 0; p_ < 2; ++p_)                           \
      BB[i_ * 2 + p_] = *(const f16x8*)(sh + 65536 + (D) * 32768 +             \
                                        p_ * 16384 + boff[(NH) * 2 + i_]);

#define MMQ(MH, NH, BB) _Pragma("unroll") for (int j_ = 0; j_ < 4; ++j_)       \
    _Pragma("unroll") for (int i_ = 0; i_ < 2; ++i_)                           \
    _Pragma("unroll") for (int k_ = 0; k_ < 2; ++k_)                           \
      acc[(MH) * 4 + j_][(NH) * 2 + i_] =                                      \
          __builtin_amdgcn_mfma_f32_16x16x32_f16(                              \
              a[j_ * 2 + k_], BB[i_ * 2 + k_],                                 \
              acc[(MH) * 4 + j_][(NH) * 2 + i_], 0, 0, 0);

#define ITER(TA, LAST) {                                                       \
    /* P0 (A0,B0) buf0 */                                                      \
    RDA(0, 0); RDB(0, 0, b0);                                                  \
    BARR; LGKM0; SBR; PRIO1; MMQ(0, 0, b0); PRIO0; BARR; SBR;                  \
    /* P1 (A0,B1): stage T+2 h0 (slots freed at P0) */                         \
    RDB(0, 1, b1); if (!(LAST)) { STA((TA) + 2, 0); STB((TA) + 2, 0); }        \
    BARR; LGKM0; SBR; PRIO1; MMQ(0, 1, b1); PRIO0; BARR; SBR;                  \
    /* P2 (A1,B1): stage T+2 B.h1 (freed at P1) */                             \
    RDA(0, 1); if (!(LAST)) STB((TA) + 2, 1);                                  \
    BARR; LGKM0; SBR; PRIO1; MMQ(1, 1, b1); PRIO0; BARR; SBR;                  \
    /* P3 (A1,B0): stage T+2 A.h1 (freed at P2) */                             \
    if (!(LAST)) STA((TA) + 2, 1);                                             \
    BARR; LGKM0; SBR; PRIO1; MMQ(1, 0, b0); PRIO0;                             \
    if (LAST) { VM0; } else { VM8; } BARR; SBR;                                \
    /* P4 (A0,B0) buf1 */                                                      \
    RDA(1, 0); RDB(1, 0, b0);                                                  \
    BARR; LGKM0; SBR; PRIO1; MMQ(0, 0, b0); PRIO0; BARR; SBR;                  \
    /* P5 (A0,B1): stage T+3 h0 */                                             \
    RDB(1, 1, b1); if (!(LAST)) { STA((TA) + 3, 0); STB((TA) + 3, 0); }        \
    BARR; LGKM0; SBR; PRIO1; MMQ(0, 1, b1); PRIO0; BARR; SBR;                  \
    /* P6 (A1,B1): stage T+3 B.h1 */                                           \
    RDA(1, 1); if (!(LAST)) STB((TA) + 3, 1);                                  \
    BARR; LGKM0; SBR; PRIO1; MMQ(1, 1, b1); PRIO0; BARR; SBR;                  \
    /* P7 (A1,B0): stage T+3 A.h1 */                                           \
    if (!(LAST)) STA((TA) + 3, 1);                                             \
    BARR; LGKM0; SBR; PRIO1; MMQ(1, 0, b0); PRIO0;                             \
    if (!(LAST)) { VM8; } BARR; SBR; }

template <int KD, int LDA, int LDB, bool ADDX>
__global__ __launch_bounds__(512, 2)
void k_gemm256(const f16* __restrict__ Ab, const f16* __restrict__ Bb,
               size_t astride, size_t bstride, float* __restrict__ Cb,
               size_t cstride, int ldc, const f16* __restrict__ Xb,
               int nbn, int perb) {
  constexpr int NT = KD / 64, NI = NT / 2;
  static_assert(KD % 128 == 0 && NT >= 4, "need even #tiles >= 4");
  __shared__ char sh[131072];
  const int tid = threadIdx.x, lane = tid & 63, wid = tid >> 6;
  const int wm = wid >> 2, wn = wid & 3;   // 2 x 4 waves

  // bijective XCD swizzle (m204): same-XCD origs -> contiguous tile ids
  const int nwg = gridDim.x, orig = blockIdx.x;
  const int qq = nwg >> 3, rr8 = nwg & 7, xcd = orig & 7;
  const int id = (xcd < rr8 ? xcd * (qq + 1) : rr8 * (qq + 1) + (xcd - rr8) * qq)
                 + (orig >> 3);
  const int z = id / perb, t = id - z * perb;
  const int bm = (t / nbn) * 256, bn = (t - (t / nbn) * nbn) * 256;

  const f16* Ap = Ab + z * astride + (size_t)bm * LDA;
  const f16* Bp = Bb + z * bstride + (size_t)bn * LDB;

  const int rq = tid >> 2;
  const int cpr = (tid & 3) ^ ((tid >> 3) & 3);
  const size_t gA0 = (size_t)rq * LDA + cpr * 8;
  const size_t gA1 = gA0 + (size_t)128 * LDA;
  const size_t gB0 = (size_t)rq * LDB + cpr * 8;
  const size_t gB1 = gB0 + (size_t)128 * LDB;

  // prologue: tiles 0 and 1, 16 loads; wait tile0 (8 remain in flight)
  STA(0, 0); STB(0, 0); STB(0, 1); STA(0, 1);
  STA(1, 0); STB(1, 0); STB(1, 1); STA(1, 1);

  int aoff[8], boff[4];
#pragma unroll
  for (int mi = 0; mi < 8; ++mi) {
    const int rt = ((mi < 4) ? wm * 64 + mi * 16
                             : 128 + wm * 64 + (mi - 4) * 16) + (lane & 15);
    aoff[mi] = rt * 64 + ((((lane >> 4) ^ (rt >> 1)) & 3) << 4);
  }
#pragma unroll
  for (int ni = 0; ni < 4; ++ni) {
    const int rb = ((ni < 2) ? wn * 32 + ni * 16
                             : 128 + wn * 32 + (ni - 2) * 16) + (lane & 15);
    boff[ni] = rb * 64 + ((((lane >> 4) ^ (rb >> 1)) & 3) << 4);
  }

  f32x4 acc[8][4] = {};
  f16x8 a[8], b0[4], b1[4];

  VM8; BARR; SBR;

  for (int it = 0; it < NI - 1; ++it) { ITER(2 * it, false); }
  ITER(2 * (NI - 1), true);

  // epilogue (residual read as f16 when ADDX)
  float* Cp = Cb + z * cstride;
  const f16* Xp = Xb + z * cstride;
#pragma unroll
  for (int mi = 0; mi < 8; ++mi) {
    const int row0 = bm + ((mi < 4) ? wm * 64 + mi * 16
                                    : 128 + wm * 64 + (mi - 4) * 16) +
                     (lane >> 4) * 4;
#pragma unroll
    for (int ni = 0; ni < 4; ++ni) {
      const int col = bn + ((ni < 2) ? wn * 32 + ni * 16
                                     : 128 + wn * 32 + (ni - 2) * 16) +
                      (lane & 15);
#pragma unroll
      for (int j = 0; j < 4; ++j) {
        const size_t idx = (size_t)(row0 + j) * ldc + col;
        float v = acc[mi][ni][j];
        if constexpr (ADDX) v += (float)Xp[idx];
        Cp[idx] = v;
      }
    }
  }
}

extern "C" void kernel_launch(void* const* d_in, const int* in_sizes, int n_in,
                              void* d_out, int out_size, void* d_ws,
                              size_t ws_size, hipStream_t stream) {
  const float* x = (const float*)d_in[0];
  float* out = (float*)d_out;
  const size_t qbytes = (size_t)C_DIM * N_DIM * sizeof(f16);   // 4.72 MB
  const size_t ebytes = (size_t)C_DIM * C_DIM * sizeof(float); // 4.19 MB
  const size_t per_batch = 2 * qbytes + ebytes;                // 13.6 MB
  int G = (int)(ws_size / per_batch);
  if (G > B_DIM) G = B_DIM;
  if (G < 1) G = 1;

  f16* qh = (f16*)d_ws;
  f16* qt = qh + (size_t)G * C_DIM * N_DIM;
  float* eng = (float*)(qt + (size_t)G * C_DIM * N_DIM);

  for (int b0 = 0; b0 < B_DIM; b0 += G) {
    const int g = (B_DIM - b0 < G) ? (B_DIM - b0) : G;
    const float* xg = x + (size_t)b0 * C_DIM * N_DIM;
    float* og = out + (size_t)b0 * C_DIM * N_DIM;

    k_cast_transpose<<<dim3(N_DIM / 64, C_DIM / 64, g), 256, 0, stream>>>(
        xg, qh, qt);

    // E = qh . qh^T  (M=N=C, K=N_DIM); 16 tiles/batch, XCD-swizzled 1D grid
    k_gemm256<N_DIM, N_DIM, N_DIM, false>
        <<<dim3(16 * g), 512, 0, stream>>>(
            qh, qh, (size_t)C_DIM * N_DIM, (size_t)C_DIM * N_DIM, eng,
            (size_t)C_DIM * C_DIM, C_DIM, nullptr, 4, 16);

    // attn = softmax(min - E) f16 in-place; one wave per row
    k_softmax<<<dim3(C_DIM / 4, g), 256, 0, stream>>>(eng);

    // out = attn . qt^T + qh(residual, f16)   (M=C, N=N_DIM, K=C)
    k_gemm256<C_DIM, 2 * C_DIM, C_DIM, true>
        <<<dim3(36 * g), 512, 0, stream>>>(
            (const f16*)eng, qt, (size_t)2 * C_DIM * C_DIM,
            (size_t)N_DIM * C_DIM, og, (size_t)C_DIM * N_DIM, N_DIM,
            qh, 9, 36);
  }
}